// Round 15
// baseline (322.897 us; speedup 1.0000x reference)
//
#include <hip/hip_runtime.h>
#include <hip/hip_bf16.h>

// R36: two low-risk latency levers on the R35 base (313.9us best).
// (1) GRU: s_setprio(1) around the MFMA cluster -- the GRU has real per-wave
//     phase diversity (gates/store vs MFMA), the regime where setprio measured
//     +4-7% (attn m191), unlike lockstep GEMM (m190 null). No numeric effect.
// (2) MLP: depth-1 double-buffer of the 8 a8 ds_read_b128 (mirror of the wf
//     prefetch; act[] is constant within a layer). Hides the ~120cyc LDS
//     latency fronting each 32-MFMA block. Reg math: a8 dbuf 64 + wf 32 +
//     addr ~30 arch + acc 128 AGPR ~= 253/256 -- spill would show as MLP
//     FETCH_SIZE ballooning.
// Floors (banked): GRU per-SIMD MFMA floor 1862 cyc/step (~99us) invariant
// to re-tiling (row-group can't span CUs); MLP occupancy capped by register
// file (R34 spill). If both levers null -> structure's ceiling, declare.

typedef __bf16 bf16_t;
typedef __bf16 bf16x2 __attribute__((ext_vector_type(2)));
typedef __bf16 bf16x4 __attribute__((ext_vector_type(4)));
typedef __bf16 bf16x8 __attribute__((ext_vector_type(8)));
typedef float f32x4 __attribute__((ext_vector_type(4)));

#define MFMA16(a, b, c) __builtin_amdgcn_mfma_f32_16x16x32_bf16(a, b, c, 0, 0, 0)

#define EMB 256
#define TSTEPS 128
#define OUTD 64

#define HS_OFF   0u           // bf16 65536x256 = 33,554,432
#define H0_OFF   33554432u    // f32 512x256   = 524,288
#define WHH_OFF  34078720u    // bf16 768x256  = 393,216
#define W1_OFF   34471936u    // bf16 512x256  = 262,144 (fragment-ordered)
#define W2_OFF   34734080u    // bf16 512x512  = 524,288 (fragment-ordered)
#define W3_OFF   35258368u    // bf16 512x512  = 524,288 (fragment-ordered)
#define MUW_OFF  35782656u    // bf16 64x512   = 65,536  (fragment-ordered)

__device__ __forceinline__ float rcpf(float x){ return __builtin_amdgcn_rcpf(x); }
__device__ __forceinline__ void lds_barrier() {
  asm volatile("s_waitcnt lgkmcnt(0)\n\ts_barrier" ::: "memory");
}
__device__ __forceinline__ float eluf(float x) {
  return (x > 0.f) ? x : (__expf(x) - 1.f);
}
__device__ __forceinline__ bf16x8 cvt8(const float* __restrict__ s) {
  const float4 a = *reinterpret_cast<const float4*>(s);
  const float4 b = *reinterpret_cast<const float4*>(s + 4);
  bf16x8 v;
  v[0] = (bf16_t)a.x; v[1] = (bf16_t)a.y; v[2] = (bf16_t)a.z; v[3] = (bf16_t)a.w;
  v[4] = (bf16_t)b.x; v[5] = (bf16_t)b.y; v[6] = (bf16_t)b.z; v[7] = (bf16_t)b.w;
  return v;
}

// ---------------------------------------------------------------------------
// Fragment layout: element (n, k) of an NxK weight, n = nt*16 + l15,
// k = kc*128 + kk*32 + quad*8 + e, lane = quad*16 + l15, lives at
//   Wf[(((nt*KC + kc)*4 + kk) << 9) + lane*8 + e]
// ---------------------------------------------------------------------------
template<int KC, int LOGKC>
__device__ __forceinline__ void conv_frag8(
    const float* __restrict__ src, bf16_t* __restrict__ dst,
    int NK8, int g, int G)
{
  const int K = KC * 128;
  for (int i8 = g; i8 < NK8; i8 += G) {
    const int l15  = i8 & 15;
    const int quad = (i8 >> 4) & 3;
    const int kk   = (i8 >> 6) & 3;
    const int rem  = i8 >> 8;
    const int kc   = rem & (KC - 1);
    const int nt   = rem >> LOGKC;
    *reinterpret_cast<bf16x8*>(dst + (size_t)i8 * 8) =
        cvt8(src + (size_t)(nt * 16 + l15) * K + kc * 128 + kk * 32 + quad * 8);
  }
}

// Fused convert + embedding: blocks 0..511 do emb rows, 512..767 do convert.
__global__ __launch_bounds__(256) void ce_kernel(
    const float* __restrict__ z_t, const float* __restrict__ z_g,
    const float* __restrict__ w_emb, float* __restrict__ h0,
    const float* __restrict__ whh, const float* __restrict__ w1,
    const float* __restrict__ w2, const float* __restrict__ w3,
    const float* __restrict__ muw, char* __restrict__ ws)
{
  const int tid = threadIdx.x;
  if (blockIdx.x < 512) {
    // ---- embedding: one bw row per WG ----
    __shared__ float zrow[128];
    const int bw = blockIdx.x;
    if (tid < 128)
      zrow[tid] = (tid < 64) ? z_t[bw * 64 + tid] : z_g[(bw >> 4) * 64 + (tid - 64)];
    __syncthreads();
    const float4* wp = reinterpret_cast<const float4*>(w_emb + (size_t)tid * 128);
    float s = 0.f;
#pragma unroll
    for (int k4 = 0; k4 < 32; ++k4) {
      const float4 w = wp[k4];
      s += zrow[k4 * 4 + 0] * w.x + zrow[k4 * 4 + 1] * w.y
         + zrow[k4 * 4 + 2] * w.z + zrow[k4 * 4 + 3] * w.w;
    }
    h0[(size_t)bw * 256 + tid] = s;
  } else {
    // ---- weight conversion (8-wide, coalesced) ----
    const int g = (blockIdx.x - 512) * 256 + tid;
    const int G = 256 * 256;
    bf16_t* d = (bf16_t*)(ws + WHH_OFF);
    for (int i8 = g; i8 < 24576; i8 += G)      // whh linear copy
      *reinterpret_cast<bf16x8*>(d + (size_t)i8 * 8) = cvt8(whh + (size_t)i8 * 8);
    conv_frag8<2, 1>(w1,  (bf16_t*)(ws + W1_OFF),  16384, g, G);
    conv_frag8<4, 2>(w2,  (bf16_t*)(ws + W2_OFF),  32768, g, G);
    conv_frag8<4, 2>(w3,  (bf16_t*)(ws + W3_OFF),  32768, g, G);
    conv_frag8<4, 2>(muw, (bf16_t*)(ws + MUW_OFF),  4096, g, G);
  }
}

// ---------------------------------------------------------------------------
// GRU: R35 + setprio around MFMA cluster. 128 WGs x 512 thr (8 waves,
// 2 waves/SIMD). 4 rows/WG at A-rows {0,4,8,12}. Wave wv owns gate cols
// cA = wv*32 + l15 (+16 for s=1) in each gate group. wfrag 6x8 (AGPR via
// compiler), acc 24. h16 row stride 272 (measured-best, 528K conflict cyc).
// ---------------------------------------------------------------------------
__global__ __launch_bounds__(512, 2) void gru_kernel(
    const float* __restrict__ h0, const bf16_t* __restrict__ w_hh,
    const float* __restrict__ b_ih, const float* __restrict__ b_hh,
    bf16_t* __restrict__ hs)
{
  __shared__ __align__(16) bf16_t h16[2][16][272];

  const int tid  = threadIdx.x;
  const int wv   = tid >> 6;      // 0..7
  const int lane = tid & 63;
  const int l15  = lane & 15;
  const int quad = lane >> 4;     // 0..3 == batch row within WG
  const int bw0  = blockIdx.x * 4;
  const int cA   = wv * 32 + l15; // col for s=0 (s=1 is cA+16)

  // register-resident W_hh: 6 tiles/wave (ct = g*2+s), 8 k-frags each
  bf16x8 wf[6][8];
#pragma unroll
  for (int g = 0; g < 3; ++g)
#pragma unroll
    for (int s = 0; s < 2; ++s) {
      const int n = g * 256 + cA + s * 16;
#pragma unroll
      for (int kk = 0; kk < 8; ++kk)
        wf[g * 2 + s][kk] = *reinterpret_cast<const bf16x8*>(
            w_hh + (size_t)n * 256 + kk * 32 + quad * 8);
    }

  // per-thread gate state: row = quad, cols cA + s*16 (s=0,1)
  float br[2], bz[2], bin[2], bhn[2], hm[2];
#pragma unroll
  for (int s = 0; s < 2; ++s) {
    const int c = cA + s * 16;
    br[s]  = b_ih[c]       + b_hh[c];
    bz[s]  = b_ih[256 + c] + b_hh[256 + c];
    bin[s] = b_ih[512 + c];
    bhn[s] = b_hh[512 + c];
    hm[s]  = h0[(size_t)(bw0 + quad) * 256 + c];
  }

  // zero both buffers (padding rows must read as 0), then seed buf 0
  {
    bf16x8 zv;
#pragma unroll
    for (int e = 0; e < 8; ++e) zv[e] = (bf16_t)0.f;
    for (int i = tid; i < 1088; i += 512)   // 2*16*272/8
      reinterpret_cast<bf16x8*>(h16)[i] = zv;
  }
  __syncthreads();
#pragma unroll
  for (int s = 0; s < 2; ++s)
    h16[0][quad * 4][cA + s * 16] = (bf16_t)hm[s];
  __syncthreads();

  bf16_t* hsp = hs + ((size_t)(bw0 + quad) * TSTEPS) * EMB + cA;

#pragma unroll 1
  for (int t = 0; t < TSTEPS; ++t) {
    const bf16_t (*hr)[272] = h16[t & 1];
    bf16_t (*hw)[272] = h16[(t & 1) ^ 1];

    f32x4 acc[6] = {};
    __builtin_amdgcn_s_setprio(1);
#pragma unroll
    for (int kk = 0; kk < 8; ++kk) {
      const bf16x8 a = *reinterpret_cast<const bf16x8*>(&hr[l15][kk * 32 + quad * 8]);
#pragma unroll
      for (int ct = 0; ct < 6; ++ct)
        acc[ct] = MFMA16(a, wf[ct][kk], acc[ct]);
    }
    __builtin_amdgcn_s_setprio(0);

    // gates fully in-register: reg 0 of each acc is the real row (m=4*quad)
#pragma unroll
    for (int s = 0; s < 2; ++s) {
      const float gr = acc[s][0]     + br[s];
      const float gz = acc[2 + s][0] + bz[s];
      const float gn = acc[4 + s][0] + bhn[s];
      const float rr = rcpf(1.f + __expf(-gr));
      const float zz = rcpf(1.f + __expf(-gz));
      const float pre = bin[s] + rr * gn;
      const float nn = 1.f - 2.f * rcpf(__expf(2.f * pre) + 1.f);
      hm[s] = nn + zz * (hm[s] - nn);
      const bf16_t nh = (bf16_t)hm[s];
      hw[quad * 4][cA + s * 16] = nh;
      hsp[(size_t)t * EMB + s * 16] = nh;
    }
    lds_barrier();   // hw writes drained; next step reads hw as hr
  }
}

// ---------------------------------------------------------------------------
// Fused MLP: 512 WGs x 512 thr (8 waves), 128 rows/WG, 137KB LDS, 1 WG/CU.
// Wave wv owns ct 0..3 -> nt = wv*4+ct, mt 0..7. Depth-1 prefetch of BOTH
// wf (global) and a8 (LDS). Swapped MFMA + b64 epilogue (R30 numerics).
// ---------------------------------------------------------------------------
template<int KC>
__device__ __forceinline__ void mlp_layer(
    const bf16_t* __restrict__ Wf, const float* __restrict__ bias,
    bf16_t (*act)[536], int wv, int lane, int l15, int quad)
{
  constexpr int NIT = KC * 4;
  f32x4 acc[4][8] = {};
  bf16x8 wf[2][4];
  bf16x8 a8[2][8];

#pragma unroll
  for (int ct = 0; ct < 4; ++ct)
    wf[0][ct] = *reinterpret_cast<const bf16x8*>(
        Wf + (((size_t)(wv * 4 + ct) * KC) << 11) + lane * 8);
#pragma unroll
  for (int mt = 0; mt < 8; ++mt)
    a8[0][mt] = *reinterpret_cast<const bf16x8*>(
        &act[mt * 16 + l15][quad * 8]);

#pragma unroll
  for (int it = 0; it < NIT; ++it) {
    const int cur = it & 1, nxt = cur ^ 1;
    if (it + 1 < NIT) {
      const int kc1 = (it + 1) >> 2, kk1 = (it + 1) & 3;
#pragma unroll
      for (int ct = 0; ct < 4; ++ct)
        wf[nxt][ct] = *reinterpret_cast<const bf16x8*>(
            Wf + ((((size_t)(wv * 4 + ct) * KC + kc1) * 4 + kk1) << 9) + lane * 8);
#pragma unroll
      for (int mt = 0; mt < 8; ++mt)
        a8[nxt][mt] = *reinterpret_cast<const bf16x8*>(
            &act[mt * 16 + l15][kc1 * 128 + kk1 * 32 + quad * 8]);
    }
#pragma unroll
    for (int mt = 0; mt < 8; ++mt)
#pragma unroll
      for (int ct = 0; ct < 4; ++ct)
        acc[ct][mt] = MFMA16(wf[cur][ct], a8[cur][mt], acc[ct][mt]);  // swapped
  }

  __syncthreads();
#pragma unroll
  for (int ct = 0; ct < 4; ++ct) {
    const int nb = (wv * 4 + ct) * 16 + quad * 4;   // 4-aligned col base
    const float4 b4 = *reinterpret_cast<const float4*>(bias + nb);
#pragma unroll
    for (int mt = 0; mt < 8; ++mt) {
      bf16x4 v;
      v[0] = (bf16_t)eluf(acc[ct][mt][0] + b4.x);
      v[1] = (bf16_t)eluf(acc[ct][mt][1] + b4.y);
      v[2] = (bf16_t)eluf(acc[ct][mt][2] + b4.z);
      v[3] = (bf16_t)eluf(acc[ct][mt][3] + b4.w);
      *reinterpret_cast<bf16x4*>(&act[mt * 16 + l15][nb]) = v;
    }
  }
  __syncthreads();
}

__global__ __launch_bounds__(512, 2) void mlp_kernel(
    const bf16_t* __restrict__ hs,
    const bf16_t* __restrict__ w1, const float* __restrict__ b1,
    const bf16_t* __restrict__ w2, const float* __restrict__ b2,
    const bf16_t* __restrict__ w3, const float* __restrict__ b3,
    const bf16_t* __restrict__ muw, const float* __restrict__ mub,
    float* __restrict__ out)
{
  __shared__ __align__(16) bf16_t act[128][536];

  const int tid  = threadIdx.x;
  const int wv   = tid >> 6;      // 0..7
  const int lane = tid & 63;
  const int l15  = lane & 15;
  const int quad = lane >> 4;
  const size_t r0 = (size_t)blockIdx.x * 128;

  for (int v = tid; v < 128 * 32; v += 512) {
    const int rr = v >> 5, cc = v & 31;
    bf16x8 x = *reinterpret_cast<const bf16x8*>(hs + (r0 + rr) * EMB + cc * 8);
    *reinterpret_cast<bf16x8*>(&act[rr][cc * 8]) = x;
  }
  __syncthreads();

  mlp_layer<2>(w1, b1, act, wv, lane, l15, quad);   // 256 -> 512
  mlp_layer<4>(w2, b2, act, wv, lane, l15, quad);   // 512 -> 512
  mlp_layer<4>(w3, b3, act, wv, lane, l15, quad);   // 512 -> 512

  // mu head (unswapped, R26/R28-proven): wave wv -> out col-tile (wv&3),
  // m-tiles (wv>>2)*4 .. +4; coalesced scalar global stores.
  f32x4 macc[4] = {};
  const int nt  = wv & 3;
  const int n   = nt * 16 + l15;
  const int mtb = (wv >> 2) * 4;
#pragma unroll
  for (int it = 0; it < 16; ++it) {
    const int kc = it >> 2, kk = it & 3;
    bf16x8 wfm = *reinterpret_cast<const bf16x8*>(
        muw + ((((size_t)nt * 4 + kc) * 4 + kk) << 9) + lane * 8);
#pragma unroll
    for (int i = 0; i < 4; ++i) {
      bf16x8 a = *reinterpret_cast<const bf16x8*>(
          &act[(mtb + i) * 16 + l15][kc * 128 + kk * 32 + quad * 8]);
      macc[i] = MFMA16(a, wfm, macc[i]);
    }
  }
  const float mb = mub[n];
#pragma unroll
  for (int i = 0; i < 4; ++i)
#pragma unroll
    for (int r = 0; r < 4; ++r)
      out[(r0 + (mtb + i) * 16 + quad * 4 + r) * OUTD + n] = macc[i][r] + mb;
}

// ---------------------------------------------------------------------------
extern "C" void kernel_launch(void* const* d_in, const int* in_sizes, int n_in,
                              void* d_out, int out_size, void* d_ws, size_t ws_size,
                              hipStream_t stream) {
  char* ws = (char*)d_ws;

  ce_kernel<<<768, 256, 0, stream>>>(
      (const float*)d_in[0], (const float*)d_in[1], (const float*)d_in[2],
      (float*)(ws + H0_OFF),
      (const float*)d_in[3], (const float*)d_in[6], (const float*)d_in[8],
      (const float*)d_in[10], (const float*)d_in[12], ws);

  gru_kernel<<<128, 512, 0, stream>>>(
      (const float*)(ws + H0_OFF), (const bf16_t*)(ws + WHH_OFF),
      (const float*)d_in[4], (const float*)d_in[5],
      (bf16_t*)(ws + HS_OFF));

  mlp_kernel<<<512, 512, 0, stream>>>(
      (const bf16_t*)(ws + HS_OFF),
      (const bf16_t*)(ws + W1_OFF), (const float*)d_in[7],
      (const bf16_t*)(ws + W2_OFF), (const float*)d_in[9],
      (const bf16_t*)(ws + W3_OFF), (const float*)d_in[11],
      (const bf16_t*)(ws + MUW_OFF), (const float*)d_in[13],
      (float*)d_out);
}

// Round 16
// 306.388 us; speedup vs baseline: 1.0539x; 1.0539x over previous
//
#include <hip/hip_runtime.h>
#include <hip/hip_bf16.h>

// R37: revert byte-identical to R35 (session best, 313.93us). R36 measured
// both remaining low-risk levers NEGATIVE: (1) GRU setprio +1.4us -- the
// GRU's waves are barrier-locked per step (lockstep-GEMM regime, m190), not
// free-running (m191); (2) MLP a8 dbuf ~-7us net -- 253/256 regs removes all
// allocator slack (same cliff as R23's 232-reg exposed latency).
// Ceiling accounting (final): ~57us fixed harness overhead (fusion-proven
// irreducible, R31) + ce ~5 + GRU 136.5 (1.37x its 1862cyc/step per-SIMD
// MFMA floor; W_hh residency fills the 512-reg/SIMD file exactly -- more
// waves spill, R23/R34) + MLP ~118 (2.7x floor; occupancy spills R34, LDS
// conflicts exonerated R32, weight BW minor R33, latency dbuf negative R36).

typedef __bf16 bf16_t;
typedef __bf16 bf16x2 __attribute__((ext_vector_type(2)));
typedef __bf16 bf16x4 __attribute__((ext_vector_type(4)));
typedef __bf16 bf16x8 __attribute__((ext_vector_type(8)));
typedef float f32x4 __attribute__((ext_vector_type(4)));

#define MFMA16(a, b, c) __builtin_amdgcn_mfma_f32_16x16x32_bf16(a, b, c, 0, 0, 0)

#define EMB 256
#define TSTEPS 128
#define OUTD 64

#define HS_OFF   0u           // bf16 65536x256 = 33,554,432
#define H0_OFF   33554432u    // f32 512x256   = 524,288
#define WHH_OFF  34078720u    // bf16 768x256  = 393,216
#define W1_OFF   34471936u    // bf16 512x256  = 262,144 (fragment-ordered)
#define W2_OFF   34734080u    // bf16 512x512  = 524,288 (fragment-ordered)
#define W3_OFF   35258368u    // bf16 512x512  = 524,288 (fragment-ordered)
#define MUW_OFF  35782656u    // bf16 64x512   = 65,536  (fragment-ordered)

__device__ __forceinline__ float rcpf(float x){ return __builtin_amdgcn_rcpf(x); }
__device__ __forceinline__ void lds_barrier() {
  asm volatile("s_waitcnt lgkmcnt(0)\n\ts_barrier" ::: "memory");
}
__device__ __forceinline__ float eluf(float x) {
  return (x > 0.f) ? x : (__expf(x) - 1.f);
}
__device__ __forceinline__ bf16x8 cvt8(const float* __restrict__ s) {
  const float4 a = *reinterpret_cast<const float4*>(s);
  const float4 b = *reinterpret_cast<const float4*>(s + 4);
  bf16x8 v;
  v[0] = (bf16_t)a.x; v[1] = (bf16_t)a.y; v[2] = (bf16_t)a.z; v[3] = (bf16_t)a.w;
  v[4] = (bf16_t)b.x; v[5] = (bf16_t)b.y; v[6] = (bf16_t)b.z; v[7] = (bf16_t)b.w;
  return v;
}

// ---------------------------------------------------------------------------
// Fragment layout: element (n, k) of an NxK weight, n = nt*16 + l15,
// k = kc*128 + kk*32 + quad*8 + e, lane = quad*16 + l15, lives at
//   Wf[(((nt*KC + kc)*4 + kk) << 9) + lane*8 + e]
// ---------------------------------------------------------------------------
template<int KC, int LOGKC>
__device__ __forceinline__ void conv_frag8(
    const float* __restrict__ src, bf16_t* __restrict__ dst,
    int NK8, int g, int G)
{
  const int K = KC * 128;
  for (int i8 = g; i8 < NK8; i8 += G) {
    const int l15  = i8 & 15;
    const int quad = (i8 >> 4) & 3;
    const int kk   = (i8 >> 6) & 3;
    const int rem  = i8 >> 8;
    const int kc   = rem & (KC - 1);
    const int nt   = rem >> LOGKC;
    *reinterpret_cast<bf16x8*>(dst + (size_t)i8 * 8) =
        cvt8(src + (size_t)(nt * 16 + l15) * K + kc * 128 + kk * 32 + quad * 8);
  }
}

// Fused convert + embedding: blocks 0..511 do emb rows, 512..767 do convert.
__global__ __launch_bounds__(256) void ce_kernel(
    const float* __restrict__ z_t, const float* __restrict__ z_g,
    const float* __restrict__ w_emb, float* __restrict__ h0,
    const float* __restrict__ whh, const float* __restrict__ w1,
    const float* __restrict__ w2, const float* __restrict__ w3,
    const float* __restrict__ muw, char* __restrict__ ws)
{
  const int tid = threadIdx.x;
  if (blockIdx.x < 512) {
    // ---- embedding: one bw row per WG ----
    __shared__ float zrow[128];
    const int bw = blockIdx.x;
    if (tid < 128)
      zrow[tid] = (tid < 64) ? z_t[bw * 64 + tid] : z_g[(bw >> 4) * 64 + (tid - 64)];
    __syncthreads();
    const float4* wp = reinterpret_cast<const float4*>(w_emb + (size_t)tid * 128);
    float s = 0.f;
#pragma unroll
    for (int k4 = 0; k4 < 32; ++k4) {
      const float4 w = wp[k4];
      s += zrow[k4 * 4 + 0] * w.x + zrow[k4 * 4 + 1] * w.y
         + zrow[k4 * 4 + 2] * w.z + zrow[k4 * 4 + 3] * w.w;
    }
    h0[(size_t)bw * 256 + tid] = s;
  } else {
    // ---- weight conversion (8-wide, coalesced) ----
    const int g = (blockIdx.x - 512) * 256 + tid;
    const int G = 256 * 256;
    bf16_t* d = (bf16_t*)(ws + WHH_OFF);
    for (int i8 = g; i8 < 24576; i8 += G)      // whh linear copy
      *reinterpret_cast<bf16x8*>(d + (size_t)i8 * 8) = cvt8(whh + (size_t)i8 * 8);
    conv_frag8<2, 1>(w1,  (bf16_t*)(ws + W1_OFF),  16384, g, G);
    conv_frag8<4, 2>(w2,  (bf16_t*)(ws + W2_OFF),  32768, g, G);
    conv_frag8<4, 2>(w3,  (bf16_t*)(ws + W3_OFF),  32768, g, G);
    conv_frag8<4, 2>(muw, (bf16_t*)(ws + MUW_OFF),  4096, g, G);
  }
}

// ---------------------------------------------------------------------------
// GRU: 128 WGs x 512 thr (8 waves, 2 waves/SIMD). 4 rows/WG at A-rows
// {0,4,8,12}. Wave wv owns gate cols cA = wv*32 + l15 (+16 for s=1) in each
// gate group. wfrag 6x8 (AGPR-resident via compiler), acc 24. h16 row stride
// 272 elems (136dw%32=8 -> measured-best layout, 528K conflict cyc).
// ---------------------------------------------------------------------------
__global__ __launch_bounds__(512, 2) void gru_kernel(
    const float* __restrict__ h0, const bf16_t* __restrict__ w_hh,
    const float* __restrict__ b_ih, const float* __restrict__ b_hh,
    bf16_t* __restrict__ hs)
{
  __shared__ __align__(16) bf16_t h16[2][16][272];

  const int tid  = threadIdx.x;
  const int wv   = tid >> 6;      // 0..7
  const int lane = tid & 63;
  const int l15  = lane & 15;
  const int quad = lane >> 4;     // 0..3 == batch row within WG
  const int bw0  = blockIdx.x * 4;
  const int cA   = wv * 32 + l15; // col for s=0 (s=1 is cA+16)

  // register-resident W_hh: 6 tiles/wave (ct = g*2+s), 8 k-frags each
  bf16x8 wf[6][8];
#pragma unroll
  for (int g = 0; g < 3; ++g)
#pragma unroll
    for (int s = 0; s < 2; ++s) {
      const int n = g * 256 + cA + s * 16;
#pragma unroll
      for (int kk = 0; kk < 8; ++kk)
        wf[g * 2 + s][kk] = *reinterpret_cast<const bf16x8*>(
            w_hh + (size_t)n * 256 + kk * 32 + quad * 8);
    }

  // per-thread gate state: row = quad, cols cA + s*16 (s=0,1)
  float br[2], bz[2], bin[2], bhn[2], hm[2];
#pragma unroll
  for (int s = 0; s < 2; ++s) {
    const int c = cA + s * 16;
    br[s]  = b_ih[c]       + b_hh[c];
    bz[s]  = b_ih[256 + c] + b_hh[256 + c];
    bin[s] = b_ih[512 + c];
    bhn[s] = b_hh[512 + c];
    hm[s]  = h0[(size_t)(bw0 + quad) * 256 + c];
  }

  // zero both buffers (padding rows must read as 0), then seed buf 0
  {
    bf16x8 zv;
#pragma unroll
    for (int e = 0; e < 8; ++e) zv[e] = (bf16_t)0.f;
    for (int i = tid; i < 1088; i += 512)   // 2*16*272/8
      reinterpret_cast<bf16x8*>(h16)[i] = zv;
  }
  __syncthreads();
#pragma unroll
  for (int s = 0; s < 2; ++s)
    h16[0][quad * 4][cA + s * 16] = (bf16_t)hm[s];
  __syncthreads();

  bf16_t* hsp = hs + ((size_t)(bw0 + quad) * TSTEPS) * EMB + cA;

#pragma unroll 1
  for (int t = 0; t < TSTEPS; ++t) {
    const bf16_t (*hr)[272] = h16[t & 1];
    bf16_t (*hw)[272] = h16[(t & 1) ^ 1];

    f32x4 acc[6] = {};
#pragma unroll
    for (int kk = 0; kk < 8; ++kk) {
      const bf16x8 a = *reinterpret_cast<const bf16x8*>(&hr[l15][kk * 32 + quad * 8]);
#pragma unroll
      for (int ct = 0; ct < 6; ++ct)
        acc[ct] = MFMA16(a, wf[ct][kk], acc[ct]);
    }

    // gates fully in-register: reg 0 of each acc is the real row (m=4*quad)
#pragma unroll
    for (int s = 0; s < 2; ++s) {
      const float gr = acc[s][0]     + br[s];
      const float gz = acc[2 + s][0] + bz[s];
      const float gn = acc[4 + s][0] + bhn[s];
      const float rr = rcpf(1.f + __expf(-gr));
      const float zz = rcpf(1.f + __expf(-gz));
      const float pre = bin[s] + rr * gn;
      const float nn = 1.f - 2.f * rcpf(__expf(2.f * pre) + 1.f);
      hm[s] = nn + zz * (hm[s] - nn);
      const bf16_t nh = (bf16_t)hm[s];
      hw[quad * 4][cA + s * 16] = nh;
      hsp[(size_t)t * EMB + s * 16] = nh;
    }
    lds_barrier();   // hw writes drained; next step reads hw as hr
  }
}

// ---------------------------------------------------------------------------
// Fused MLP: 512 WGs x 512 thr (8 waves), 128 rows/WG, 137KB LDS, 1 WG/CU.
// Wave wv owns ct 0..3 -> nt = wv*4+ct (32 col-tiles), mt 0..7 (128 rows):
// 4 wf loads + 8 a8 loads per 32 MFMA. Depth-1 wf prefetch. Swapped MFMA +
// b64 epilogue (R30-proven numerics).
// ---------------------------------------------------------------------------
template<int KC>
__device__ __forceinline__ void mlp_layer(
    const bf16_t* __restrict__ Wf, const float* __restrict__ bias,
    bf16_t (*act)[536], int wv, int lane, int l15, int quad)
{
  constexpr int NIT = KC * 4;
  f32x4 acc[4][8] = {};
  bf16x8 wf[2][4];

#pragma unroll
  for (int ct = 0; ct < 4; ++ct)
    wf[0][ct] = *reinterpret_cast<const bf16x8*>(
        Wf + (((size_t)(wv * 4 + ct) * KC) << 11) + lane * 8);

#pragma unroll
  for (int it = 0; it < NIT; ++it) {
    const int cur = it & 1, nxt = cur ^ 1;
    if (it + 1 < NIT) {
      const int kc1 = (it + 1) >> 2, kk1 = (it + 1) & 3;
#pragma unroll
      for (int ct = 0; ct < 4; ++ct)
        wf[nxt][ct] = *reinterpret_cast<const bf16x8*>(
            Wf + ((((size_t)(wv * 4 + ct) * KC + kc1) * 4 + kk1) << 9) + lane * 8);
    }
    const int kc = it >> 2, kk = it & 3;
    bf16x8 a8[8];
#pragma unroll
    for (int mt = 0; mt < 8; ++mt)
      a8[mt] = *reinterpret_cast<const bf16x8*>(
          &act[mt * 16 + l15][kc * 128 + kk * 32 + quad * 8]);
#pragma unroll
    for (int mt = 0; mt < 8; ++mt)
#pragma unroll
      for (int ct = 0; ct < 4; ++ct)
        acc[ct][mt] = MFMA16(wf[cur][ct], a8[mt], acc[ct][mt]);  // swapped
  }

  __syncthreads();
#pragma unroll
  for (int ct = 0; ct < 4; ++ct) {
    const int nb = (wv * 4 + ct) * 16 + quad * 4;   // 4-aligned col base
    const float4 b4 = *reinterpret_cast<const float4*>(bias + nb);
#pragma unroll
    for (int mt = 0; mt < 8; ++mt) {
      bf16x4 v;
      v[0] = (bf16_t)eluf(acc[ct][mt][0] + b4.x);
      v[1] = (bf16_t)eluf(acc[ct][mt][1] + b4.y);
      v[2] = (bf16_t)eluf(acc[ct][mt][2] + b4.z);
      v[3] = (bf16_t)eluf(acc[ct][mt][3] + b4.w);
      *reinterpret_cast<bf16x4*>(&act[mt * 16 + l15][nb]) = v;
    }
  }
  __syncthreads();
}

__global__ __launch_bounds__(512, 2) void mlp_kernel(
    const bf16_t* __restrict__ hs,
    const bf16_t* __restrict__ w1, const float* __restrict__ b1,
    const bf16_t* __restrict__ w2, const float* __restrict__ b2,
    const bf16_t* __restrict__ w3, const float* __restrict__ b3,
    const bf16_t* __restrict__ muw, const float* __restrict__ mub,
    float* __restrict__ out)
{
  __shared__ __align__(16) bf16_t act[128][536];

  const int tid  = threadIdx.x;
  const int wv   = tid >> 6;      // 0..7
  const int lane = tid & 63;
  const int l15  = lane & 15;
  const int quad = lane >> 4;
  const size_t r0 = (size_t)blockIdx.x * 128;

  for (int v = tid; v < 128 * 32; v += 512) {
    const int rr = v >> 5, cc = v & 31;
    bf16x8 x = *reinterpret_cast<const bf16x8*>(hs + (r0 + rr) * EMB + cc * 8);
    *reinterpret_cast<bf16x8*>(&act[rr][cc * 8]) = x;
  }
  __syncthreads();

  mlp_layer<2>(w1, b1, act, wv, lane, l15, quad);   // 256 -> 512
  mlp_layer<4>(w2, b2, act, wv, lane, l15, quad);   // 512 -> 512
  mlp_layer<4>(w3, b3, act, wv, lane, l15, quad);   // 512 -> 512

  // mu head (unswapped, R26/R28-proven): wave wv -> out col-tile (wv&3),
  // m-tiles (wv>>2)*4 .. +4; coalesced scalar global stores.
  f32x4 macc[4] = {};
  const int nt  = wv & 3;
  const int n   = nt * 16 + l15;
  const int mtb = (wv >> 2) * 4;
#pragma unroll
  for (int it = 0; it < 16; ++it) {
    const int kc = it >> 2, kk = it & 3;
    bf16x8 wfm = *reinterpret_cast<const bf16x8*>(
        muw + ((((size_t)nt * 4 + kc) * 4 + kk) << 9) + lane * 8);
#pragma unroll
    for (int i = 0; i < 4; ++i) {
      bf16x8 a = *reinterpret_cast<const bf16x8*>(
          &act[(mtb + i) * 16 + l15][kc * 128 + kk * 32 + quad * 8]);
      macc[i] = MFMA16(a, wfm, macc[i]);
    }
  }
  const float mb = mub[n];
#pragma unroll
  for (int i = 0; i < 4; ++i)
#pragma unroll
    for (int r = 0; r < 4; ++r)
      out[(r0 + (mtb + i) * 16 + quad * 4 + r) * OUTD + n] = macc[i][r] + mb;
}

// ---------------------------------------------------------------------------
extern "C" void kernel_launch(void* const* d_in, const int* in_sizes, int n_in,
                              void* d_out, int out_size, void* d_ws, size_t ws_size,
                              hipStream_t stream) {
  char* ws = (char*)d_ws;

  ce_kernel<<<768, 256, 0, stream>>>(
      (const float*)d_in[0], (const float*)d_in[1], (const float*)d_in[2],
      (float*)(ws + H0_OFF),
      (const float*)d_in[3], (const float*)d_in[6], (const float*)d_in[8],
      (const float*)d_in[10], (const float*)d_in[12], ws);

  gru_kernel<<<128, 512, 0, stream>>>(
      (const float*)(ws + H0_OFF), (const bf16_t*)(ws + WHH_OFF),
      (const float*)d_in[4], (const float*)d_in[5],
      (bf16_t*)(ws + HS_OFF));

  mlp_kernel<<<512, 512, 0, stream>>>(
      (const bf16_t*)(ws + HS_OFF),
      (const bf16_t*)(ws + W1_OFF), (const float*)d_in[7],
      (const bf16_t*)(ws + W2_OFF), (const float*)d_in[9],
      (const bf16_t*)(ws + W3_OFF), (const float*)d_in[11],
      (const bf16_t*)(ws + MUW_OFF), (const float*)d_in[13],
      (float*)d_out);
}